// Round 2
// baseline (329.789 us; speedup 1.0000x reference)
//
#include <hip/hip_runtime.h>

#define TAU 1e-3f

typedef __attribute__((ext_vector_type(8))) short bf16x8;
typedef __attribute__((ext_vector_type(4))) float f32x4;

#define GLOAD_LDS16(g, l)                                      \
  __builtin_amdgcn_global_load_lds(                            \
      (const __attribute__((address_space(1))) void*)(g),      \
      (__attribute__((address_space(3))) void*)(l), 16, 0, 0)

// ---------------- kernel 0: split W fp32 -> bf16 hi/lo (truncation) --------
__global__ __launch_bounds__(256) void wconv(const float* __restrict__ W,
                                             unsigned short* __restrict__ Whi,
                                             unsigned short* __restrict__ Wlo) {
  int i = (blockIdx.x * 256 + threadIdx.x) * 4;  // grid 128*256*4 = 131072 exact
  float4 f = *(const float4*)(W + i);
  float fv[4] = {f.x, f.y, f.z, f.w};
  unsigned short h[4], l[4];
#pragma unroll
  for (int j = 0; j < 4; ++j) {
    unsigned u = __float_as_uint(fv[j]);
    h[j] = (unsigned short)(u >> 16);
    float r = fv[j] - __uint_as_float(u & 0xffff0000u);
    l[j] = (unsigned short)(__float_as_uint(r) >> 16);
  }
  *(ushort4*)(Whi + i) = make_ushort4(h[0], h[1], h[2], h[3]);
  *(ushort4*)(Wlo + i) = make_ushort4(l[0], l[1], l[2], l[3]);
}

// ---------------- kernel 1: main gate ------------------------------------
// grid 1024 x 256 threads (4 waves). Block: 16 tokens. Wave w: experts [16w,16w+16).
__global__ __launch_bounds__(256) void gate_main(
    const float* __restrict__ x, const float* __restrict__ Wf,
    const unsigned short* __restrict__ Whi, const unsigned short* __restrict__ Wlo,
    float* __restrict__ out, float* __restrict__ accum) {
  // pitch 260 floats = 1040 B: 16B-aligned, 4 dwords mod 32 -> 2-way (free) ds_read
  __shared__ __align__(16) float xs[2][16][260];
  __shared__ __align__(16) float lg[16][68];
  __shared__ float m2s[16], m1s[16], izs[16];
  __shared__ int i1s[16], i2s[16];

  const int tid = threadIdx.x;
  const int lane = tid & 63;
  const int w = tid >> 6;
  const int tok0 = blockIdx.x * 16;
  const int fm = lane & 15;  // A row (token) / B row (expert) / C col
  const int kg = lane >> 4;  // k-group

  const unsigned short* bhp = Whi + (size_t)(w * 16 + fm) * 2048 + kg * 8;
  const unsigned short* blp = Wlo + (size_t)(w * 16 + fm) * 2048 + kg * 8;

  f32x4 acc = {0.f, 0.f, 0.f, 0.f};

  // ---- K loop: 8 chunks of BK=256, double-buffered LDS ----
  {
    const int r0 = w * 4;
    // stage chunk 0
    {
      const float* g0 = x + (size_t)(tok0 + r0) * 2048 + lane * 4;
#pragma unroll
      for (int i = 0; i < 4; ++i)
        GLOAD_LDS16(g0 + (size_t)i * 2048, &xs[0][r0 + i][0]);
    }
    for (int c = 0; c < 8; ++c) {
      __syncthreads();  // chunk c staged (each wave drains its own vmcnt)
      if (c < 7) {
        const float* g0 = x + (size_t)(tok0 + r0) * 2048 + (c + 1) * 256 + lane * 4;
        int nb = (c + 1) & 1;
#pragma unroll
        for (int i = 0; i < 4; ++i)
          GLOAD_LDS16(g0 + (size_t)i * 2048, &xs[nb][r0 + i][0]);
      }
      const int buf = c & 1;
#pragma unroll
      for (int s = 0; s < 8; ++s) {
        const float* ap = &xs[buf][fm][s * 32 + kg * 8];
        float4 fa = *(const float4*)ap;
        float4 fb = *(const float4*)(ap + 4);
        float fv[8] = {fa.x, fa.y, fa.z, fa.w, fb.x, fb.y, fb.z, fb.w};
        bf16x8 ah, al;
#pragma unroll
        for (int j = 0; j < 8; ++j) {
          unsigned u = __float_as_uint(fv[j]);
          ah[j] = (short)(u >> 16);
          float r = fv[j] - __uint_as_float(u & 0xffff0000u);
          al[j] = (short)(__float_as_uint(r) >> 16);
        }
        const int off = c * 256 + s * 32;
        bf16x8 bh = *(const bf16x8*)(bhp + off);
        bf16x8 bl = *(const bf16x8*)(blp + off);
        acc = __builtin_amdgcn_mfma_f32_16x16x32_bf16(ah, bh, acc, 0, 0, 0);
        acc = __builtin_amdgcn_mfma_f32_16x16x32_bf16(ah, bl, acc, 0, 0, 0);
        acc = __builtin_amdgcn_mfma_f32_16x16x32_bf16(al, bh, acc, 0, 0, 0);
      }
    }
  }

  // ---- C to LDS: row(token) = kg*4+r, col(expert) = w*16+fm ----
#pragma unroll
  for (int r = 0; r < 4; ++r) lg[kg * 4 + r][w * 16 + fm] = acc[r];
  __syncthreads();

  if (w != 0) return;  // wave 0 does the epilogue (no further __syncthreads)

  const int t = lane;
  // ---- phase A: approx top-3 scan, flag near-ties ----
  float m1 = -3e38f, m2 = -3e38f, m3 = -3e38f;
  int i1 = 0, i2 = 0;
  if (lane < 16) {
    for (int e = 0; e < 64; ++e) {
      float v = lg[t][e];
      if (v > m1) { m3 = m2; m2 = m1; i2 = i1; m1 = v; i1 = e; }
      else if (v > m2) { m3 = m2; m2 = v; i2 = e; }
      else if (v > m3) { m3 = v; }
    }
    m2s[t] = m2;
  }
  bool flg = (lane < 16) && ((m1 - m2 < TAU) || (m2 - m3 < TAU));
  unsigned long long msk = __ballot(flg);

  // ---- exact fp32 fixup for near-tie tokens (candidate experts only) ----
  while (msk) {
    int tt = __ffsll(msk) - 1;
    msk &= msk - 1;
    float thr = m2s[tt] - TAU;
    if (lg[tt][lane] >= thr) {
      const float* xr = x + (size_t)(tok0 + tt) * 2048;
      const float* wr = Wf + (size_t)lane * 2048;
      float s0 = 0.f, s1 = 0.f, s2 = 0.f, s3 = 0.f;
      for (int k = 0; k < 2048; k += 8) {
        float4 a0 = *(const float4*)(xr + k);
        float4 b0 = *(const float4*)(wr + k);
        float4 a1 = *(const float4*)(xr + k + 4);
        float4 b1 = *(const float4*)(wr + k + 4);
        s0 += a0.x * b0.x + a0.y * b0.y;
        s1 += a0.z * b0.z + a0.w * b0.w;
        s2 += a1.x * b1.x + a1.y * b1.y;
        s3 += a1.z * b1.z + a1.w * b1.w;
      }
      lg[tt][lane] = (s0 + s1) + (s2 + s3);
    }
  }

  // ---- rescan + outputs ----
  if (lane < 16) {
    m1 = -3e38f; m2 = -3e38f; i1 = 0; i2 = 0;
    for (int e = 0; e < 64; ++e) {
      float v = lg[t][e];
      if (v > m1) { m2 = m1; i2 = i1; m1 = v; i1 = e; }
      else if (v > m2) { m2 = v; i2 = e; }
    }
    float Z = 0.f;
    for (int e = 0; e < 64; ++e) Z += __expf(lg[t][e] - m1);
    float iz = 1.f / Z;
    float p1 = iz;                    // exp(m1-m1)*iz
    float p2 = __expf(m2 - m1) * iz;
    float dn = 1.f / (p1 + p2 + 1e-20f);
    size_t tg = (size_t)(tok0 + t);
    out[tg * 2 + 0] = (float)i1;
    out[tg * 2 + 1] = (float)i2;
    out[32768 + tg * 2 + 0] = p1 * dn;
    out[32768 + tg * 2 + 1] = p2 * dn;
    m1s[t] = m1; izs[t] = iz; i1s[t] = i1; i2s[t] = i2;
  }

  // ---- phase B/C: per-(batch,expert) score sums + top2 counts ----
  const int b = blockIdx.x >> 8;  // 256 blocks per batch row
  float ssum = 0.f;
  int cnt = 0;
#pragma unroll
  for (int t2 = 0; t2 < 16; ++t2) {
    ssum += __expf(lg[t2][lane] - m1s[t2]) * izs[t2];
    cnt += (i1s[t2] == lane) + (i2s[t2] == lane);
  }
  atomicAdd(&accum[b * 64 + lane], ssum);
  atomicAdd(&accum[256 + b * 64 + lane], (float)cnt);
}

// ---------------- kernel 2: aux loss finalize -----------------------------
__global__ __launch_bounds__(256) void gate_fin(const float* __restrict__ accum,
                                                float* __restrict__ out) {
  int tid = threadIdx.x;
  int b = tid >> 6, e = tid & 63;
  // ce = cnt * E/(S*K) = cnt/128 ; expert_scores = ssum/4096
  float v = accum[256 + b * 64 + e] * (1.f / 128.f) *
            (accum[b * 64 + e] * (1.f / 4096.f));
  for (int o = 32; o; o >>= 1) v += __shfl_xor(v, o, 64);
  __shared__ float red[4];
  if (e == 0) red[b] = v;
  __syncthreads();
  if (tid == 0) out[65536] = 0.025f * (red[0] + red[1] + red[2] + red[3]);  // 0.1/4
}

extern "C" void kernel_launch(void* const* d_in, const int* in_sizes, int n_in,
                              void* d_out, int out_size, void* d_ws, size_t ws_size,
                              hipStream_t stream) {
  const float* x = (const float*)d_in[0];
  const float* Wf = (const float*)d_in[1];
  float* out = (float*)d_out;
  unsigned short* Whi = (unsigned short*)d_ws;
  unsigned short* Wlo = Whi + 64 * 2048;
  float* accum = (float*)((char*)d_ws + 64 * 2048 * 2 * sizeof(unsigned short));
  hipMemsetAsync(accum, 0, 512 * sizeof(float), stream);
  wconv<<<128, 256, 0, stream>>>(Wf, Whi, Wlo);
  gate_main<<<1024, 256, 0, stream>>>(x, Wf, Whi, Wlo, out, accum);
  gate_fin<<<1, 256, 0, stream>>>(accum, out);
}